// Round 3
// baseline (436.102 us; speedup 1.0000x reference)
//
#include <hip/hip_runtime.h>
#include <hip/hip_bf16.h>
#include <cmath>

typedef unsigned short u16;
typedef unsigned int   u32;

using v4f    = __attribute__((ext_vector_type(4)))  float;
using f32x16 = __attribute__((ext_vector_type(16))) float;
using s8v    = __attribute__((ext_vector_type(8)))  short;
using u32x2  = __attribute__((ext_vector_type(2)))  unsigned int;

union Frag { uint4 u; s8v s; };

__device__ __forceinline__ u16 f2bf(float f){
  u32 u = __float_as_uint(f);
  u32 r = u + 0x7fffu + ((u >> 16) & 1u);
  return (u16)(r >> 16);
}
__device__ __forceinline__ float bf2f(u16 h){ return __uint_as_float(((u32)h) << 16); }

// pack two f32 -> one dword of 2 bf16 (RNE), single VALU op (T12 recipe; no builtin on gfx950)
__device__ __forceinline__ u32 cvtpk(float a, float b){
  u32 r;
  asm("v_cvt_pk_bf16_f32 %0, %1, %2" : "=v"(r) : "v"(a), "v"(b));
  return r;
}

// async global->LDS, 16B per lane; LDS dest is wave-uniform base + lane*16
__device__ __forceinline__ void async16(const void* g, void* l){
  __builtin_amdgcn_global_load_lds((__attribute__((address_space(1))) void*)g,
                                   (__attribute__((address_space(3))) void*)l, 16, 0, 0);
}

// ---------------- cast x (fp32 -> bf16) ----------------
__global__ __launch_bounds__(256) void cast_x_kernel(const float* __restrict__ x, u16* __restrict__ xb){
  size_t i = ((size_t)blockIdx.x * 256 + threadIdx.x) * 4;
  float4 v = *(const float4*)(x + i);
  uint2 o;
  o.x = (u32)f2bf(v.x) | ((u32)f2bf(v.y) << 16);
  o.y = (u32)f2bf(v.z) | ((u32)f2bf(v.w) << 16);
  *(uint2*)(xb + i) = o;
}

// ---------------- cast + transpose weights: W[k][n] fp32 -> WT[n][k] bf16 ----------------
__global__ __launch_bounds__(256) void cast_transpose_kernel(
    const float* __restrict__ W0, const float* __restrict__ W1,
    const float* __restrict__ W2, const float* __restrict__ W3,
    u16* __restrict__ T0, u16* __restrict__ T1, u16* __restrict__ T2, u16* __restrict__ T3){
  __shared__ float tile[64][65];
  const float* W = (blockIdx.z==0)?W0:(blockIdx.z==1)?W1:(blockIdx.z==2)?W2:W3;
  u16*         T = (blockIdx.z==0)?T0:(blockIdx.z==1)?T1:(blockIdx.z==2)?T2:T3;
  const int k0 = blockIdx.y*64, n0 = blockIdx.x*64;
  const int t  = threadIdx.x;
  const int rr = t >> 4, c4 = (t & 15) * 4;
  #pragma unroll
  for (int i=0;i<4;i++){
    int k = rr + i*16;
    float4 v = *(const float4*)(W + (size_t)(k0+k)*2048 + n0 + c4);
    tile[k][c4+0]=v.x; tile[k][c4+1]=v.y; tile[k][c4+2]=v.z; tile[k][c4+3]=v.w;
  }
  __syncthreads();
  #pragma unroll
  for (int i=0;i<4;i++){
    int n = rr + i*16;
    uint2 o;
    o.x = (u32)f2bf(tile[c4+0][n]) | ((u32)f2bf(tile[c4+1][n])<<16);
    o.y = (u32)f2bf(tile[c4+2][n]) | ((u32)f2bf(tile[c4+3][n])<<16);
    *(uint2*)(T + (size_t)(n0+n)*2048 + k0 + c4) = o;
  }
}

// ---------------- bf16 MFMA GEMM (m97-style): C[4096][2048] = A * BT^T + bias ----------------
// LDS tiles 128x64 u16, unpadded, 16B-block XOR swizzle: data block b of row r stored at pos b^(r&7).
// MODE 0: bf16 output row-major [4096][2048]. MODE 1: fp32 output row-major.
template<int MODE>
__global__ __launch_bounds__(256) void gemm_kernel(const u16* __restrict__ A,
                                                   const u16* __restrict__ BT,
                                                   const float* __restrict__ bias,
                                                   void* __restrict__ Cout){
  constexpr int K = 2048;
  __shared__ u16 Asl[128*64];
  __shared__ u16 Bsl[128*64];
  const int tid  = threadIdx.x;
  const int w    = tid >> 6;
  const int lane = tid & 63;
  const int r    = lane & 15, q = lane >> 4;
  const int m0   = blockIdx.y * 128;
  const int n0   = blockIdx.x * 128;
  const int wm   = (w >> 1) * 64, wn = (w & 1) * 64;

  v4f acc[4][4];
  #pragma unroll
  for (int i=0;i<4;i++)
    #pragma unroll
    for (int j=0;j<4;j++) acc[i][j] = (v4f)0.f;

  // staging geometry: per instr 8 rows x 8 blocks; wave w covers rows [w*32, w*32+32)
  const int srow = w*32 + (lane>>3);
  const int sblk = (lane&7) ^ ((lane>>3)&7);   // swizzled source block for this lane's LDS slot
  const u16* Ag = A  + (size_t)(m0+srow)*K + sblk*8;
  const u16* Bg = BT + (size_t)(n0+srow)*K + sblk*8;
  u16* Als = Asl + (w*32)*64;
  u16* Bls = Bsl + (w*32)*64;

  for (int kk = 0; kk < K; kk += 64) {
    #pragma unroll
    for (int i=0;i<4;i++){
      async16(Ag + (size_t)i*8*K + kk, Als + i*512);
      async16(Bg + (size_t)i*8*K + kk, Bls + i*512);
    }
    __syncthreads();
    #pragma unroll
    for (int ks=0; ks<2; ++ks) {
      s8v af[4], bfr[4];
      #pragma unroll
      for (int i=0;i<4;i++){
        int rho = wm + i*16 + r;
        int p = (ks*4 + q) ^ (r&7);
        Frag t; t.u = *(const uint4*)(Asl + rho*64 + p*8); af[i] = t.s;
      }
      #pragma unroll
      for (int j=0;j<4;j++){
        int rho = wn + j*16 + r;
        int p = (ks*4 + q) ^ (r&7);
        Frag t; t.u = *(const uint4*)(Bsl + rho*64 + p*8); bfr[j] = t.s;
      }
      #pragma unroll
      for (int i=0;i<4;i++)
        #pragma unroll
        for (int j=0;j<4;j++)
          acc[i][j] = __builtin_amdgcn_mfma_f32_16x16x32_bf16(af[i], bfr[j], acc[i][j], 0, 0, 0);
    }
    __syncthreads();
  }

  float bv[4];
  #pragma unroll
  for (int j=0;j<4;j++) bv[j] = bias[n0 + wn + j*16 + r];

  #pragma unroll
  for (int i=0;i<4;i++){
    #pragma unroll
    for (int j=0;j<4;j++){
      const int gn = n0 + wn + j*16 + r;
      #pragma unroll
      for (int rr2=0; rr2<4; ++rr2){
        const int gm = m0 + wm + i*16 + q*4 + rr2;
        float val = acc[i][j][rr2] + bv[j];
        if (MODE == 0) ((u16*)Cout)[(size_t)gm*2048 + gn] = f2bf(val);
        else           ((float*)Cout)[(size_t)gm*2048 + gn] = val;
      }
    }
  }
}

// ---------------- RoPE in place on bf16 [B,S,H,D], one wave per (b,s,h) row ----------------
__global__ __launch_bounds__(256) void rope_kernel(u16* __restrict__ Q, u16* __restrict__ Kb){
  const int wrow = blockIdx.x*4 + (threadIdx.x >> 6);  // 0 .. 65535 over (b,s,h)
  const int lane = threadIdx.x & 63;
  u16* P = (blockIdx.y == 0) ? Q : Kb;
  const int s = (wrow >> 4) & 2047;
  const size_t base = (size_t)wrow * 128;
  float invf = exp2f(-(float)lane * 0.20762050593045952f);  // log2(10000)/64
  float angle = (float)s * invf;
  float sn, cs;
  sincosf(angle, &sn, &cs);
  float x_j   = bf2f(P[base + lane]);
  float x_j64 = bf2f(P[base + 64 + lane]);
  float x_2j  = bf2f(P[base + 2*lane]);
  float x_2j1 = bf2f(P[base + 2*lane + 1]);
  float o0 = x_j  * cs - x_2j1 * sn;
  float o1 = x_j64 * cs + x_2j  * sn;
  P[base + lane]      = f2bf(o0);
  P[base + 64 + lane] = f2bf(o1);
}

// ---------------- transpose V: [B,S,H,D] -> VT [B,H,D,S] ----------------
__global__ __launch_bounds__(256) void transpose_v_kernel(const u16* __restrict__ V, u16* __restrict__ VT){
  __shared__ u16 t[64*72];
  const int s0 = blockIdx.x*64;
  const int d0 = blockIdx.y*64;
  const int bh = blockIdx.z;
  const int b = bh >> 4, h = bh & 15;
  const size_t obase = ((size_t)bh*128 + d0)*2048 + s0;
  const int tid = threadIdx.x;
  #pragma unroll
  for (int i=0;i<2;i++){
    int c = tid + i*256;
    int sl = c >> 3, dc = (c & 7) * 8;
    *(uint4*)(t + sl*72 + dc) =
      *(const uint4*)(V + ((size_t)(b*2048 + s0 + sl))*2048 + h*128 + d0 + dc);
  }
  __syncthreads();
  #pragma unroll
  for (int i=0;i<2;i++){
    int c = tid + i*256;
    int dl = c >> 3, sc4 = (c & 7) * 8;
    u16 tmp[8];
    #pragma unroll
    for (int j=0;j<8;j++) tmp[j] = t[(sc4+j)*72 + dl];
    *(uint4*)(VT + obase + (size_t)dl*2048 + sc4) = *(const uint4*)tmp;
  }
}

// ---------------- flash attention v3: double-buffered K/V, in-register softmax ----------------
// 32x32x16 MFMA. Q-tile 128 (4 waves x 32 q-rows), K-tile 64. LDS 64KB: 2 x {K [64][128] + V [128][64]},
// unpadded with 16B-block XOR swizzle (pos = blk ^ (row&7)).
// 2-phase pipeline: stage tile t+1 into buf^1 BEFORE computing tile t; one barrier per iter
// (compiler's vmcnt(0) drain at the barrier = pipeline wait, issued a full compute-phase early).
// Swapped QK^T: S^T = mfma(A=K, B=Q); P^T frags via v_cvt_pk_bf16_f32 + permlane32_swap;
// O^T = mfma(A=V^T, B=P^T) -> lane-local 1/l normalization.
__global__ __launch_bounds__(256,2) void attn_kernel(const u16* __restrict__ Q,
                                                     const u16* __restrict__ K,
                                                     const u16* __restrict__ VT,
                                                     const int* __restrict__ mask,
                                                     u16* __restrict__ Out){
  constexpr int S = 2048;
  constexpr float SL2 = 0.08838834764831845f * 1.4426950408889634f;  // 1/sqrt(128) * log2(e)
  __shared__ u16 smem[32768];          // 64 KB: two 32KB buffers

  const int tid = threadIdx.x, w = tid >> 6, lane = tid & 63;
  const int qc = lane & 31;            // owned q-row; also key-row / d-row for A-frag reads
  const int h  = lane >> 5;            // k-slice half (A/B frag: k = 8*h + j)
  const int l7 = lane & 7;
  const int hh = blockIdx.y, b = blockIdx.z;
  const int q0 = blockIdx.x * 128;
  const size_t rowb = (size_t)b * 2048;
  const size_t bhD  = ((size_t)(b*16 + hh)) * 128;

  // Q fragments (B-operand: col = q = qc, k = d = 16t + 8h + j) straight from global (read once)
  s8v qf[8];
  {
    const u16* qp = Q + (rowb + q0 + w*32 + qc)*2048 + hh*128 + h*8;
    #pragma unroll
    for (int t=0;t<8;t++){ Frag f; f.u = *(const uint4*)(qp + t*16); qf[t] = f.s; }
  }

  f32x16 accO[4];                      // O^T: [d-block][16 regs]; row=d local, col=q=qc
  #pragma unroll
  for (int d=0; d<4; d++) accO[d] = (f32x16)0.f;
  float lsum = 0.f;

  const int sr4 = lane >> 4, sp16 = lane & 15;   // K staging: 4 rows x 16 blocks per instr
  const int vr8 = lane >> 3, vp8 = lane & 7;     // V staging: 8 rows x 8 blocks per instr

  // stage K tile [64][128] + V tile [128][64] for key block at key0 into buffer `base`
  auto stage = [&](u16* base, int key0){
    u16* Kd = base;
    u16* Vd = base + 8192;
    #pragma unroll
    for (int i=0;i<4;i++){
      int R = w*16 + i*4;
      int ob = sp16 ^ ((R&7) + sr4);              // (R+sr4)&7: R&7 in {0,4}, sr4<4
      async16(K + (rowb + key0 + R + sr4)*2048 + hh*128 + ob*8, Kd + R*128);
    }
    #pragma unroll
    for (int i=0;i<4;i++){
      int R = w*32 + i*8;
      int ob = vp8 ^ vr8;                         // (R&7)==0
      async16(VT + (bhD + R + vr8)*2048 + key0 + ob*8, Vd + R*64);
    }
  };

  // ---- prologue: stage tile 0, mask row 0 ----
  stage(smem, 0);
  int mv = mask[b*S + lane];
  __syncthreads();                                 // drains vmcnt -> buf0 ready
  unsigned long long bm = __ballot(mv != 0);
  int cur = 0;

  for (int it=0; it<32; ++it){
    // ---- issue next tile's loads before compute (2-phase pipeline) ----
    if (it < 31){
      stage(smem + (cur^1)*16384, (it+1)*64);
      mv = mask[b*S + (it+1)*64 + lane];
    }
    const u16* Ks = smem + cur*16384;              // [64 keys][128 d]
    const u16* Vs = Ks + 8192;                     // [128 d][64 keys]

    #pragma unroll
    for (int nb=0; nb<2; ++nb){
      // ---- S^T[key=nb*32+..][q] = K Q^T ----
      f32x16 sc = (f32x16)0.f;
      __builtin_amdgcn_s_setprio(1);
      #pragma unroll
      for (int t=0;t<8;t++){
        Frag kf; kf.u = *(const uint4*)(Ks + (nb*32 + qc)*128 + (((2*t + h) ^ l7)*8));
        sc = __builtin_amdgcn_mfma_f32_32x32x16_bf16(kf.s, qf[t], sc, 0, 0, 0);
      }
      __builtin_amdgcn_s_setprio(0);
      // ---- P = exp(score/sqrt(d)) (no-max softmax), lane-local row sum ----
      float p[16];
      #pragma unroll
      for (int m=0; m<16; ++m) p[m] = exp2f(sc[m] * SL2);
      if (bm != ~0ull){                            // wave-uniform fast path: mask all valid
        #pragma unroll
        for (int m=0; m<16; ++m){
          int bit = nb*32 + (m&3) + 8*(m>>2) + 4*h;
          if (!((bm >> bit) & 1ull)) p[m] = 0.f;
        }
      }
      #pragma unroll
      for (int m=0; m<16; ++m) lsum += p[m];

      // ---- build P^T B-frags in-register and do PV ----
      #pragma unroll
      for (int g=0; g<2; ++g){                     // 16-key sub-tile -> one frag
        u32 a0 = cvtpk(p[8*g+0], p[8*g+1]);        // keys 4h+{0,1}   (+16g local)
        u32 a1 = cvtpk(p[8*g+2], p[8*g+3]);        // keys 4h+{2,3}
        u32 a2 = cvtpk(p[8*g+4], p[8*g+5]);        // keys 8+4h+{0,1}
        u32 a3 = cvtpk(p[8*g+6], p[8*g+7]);        // keys 8+4h+{2,3}
        u32x2 r0 = __builtin_amdgcn_permlane32_swap(a0, a2, false, false);
        u32x2 r1 = __builtin_amdgcn_permlane32_swap(a1, a3, false, false);
        // frag elems j=0..7 = P[qc][16T + 8h + j]
        Frag pf; pf.u = make_uint4(r0[0], r1[0], r0[1], r1[1]);
        const int T = nb*2 + g;
        __builtin_amdgcn_s_setprio(1);
        #pragma unroll
        for (int d=0; d<4; ++d){
          Frag vf; vf.u = *(const uint4*)(Vs + (d*32 + qc)*64 + (((2*T + h) ^ l7)*8));
          accO[d] = __builtin_amdgcn_mfma_f32_32x32x16_bf16(vf.s, pf.s, accO[d], 0, 0, 0);
        }
        __builtin_amdgcn_s_setprio(0);
      }
    }
    __syncthreads();                               // all waves done with buf[cur]; buf[cur^1] staged
    bm = __ballot(mv != 0);
    cur ^= 1;
  }

  // ---- row sum across the two k-slice halves, normalize, store ----
  float sall = lsum + __shfl_xor(lsum, 32, 64);
  float invv = (sall > 0.f) ? 1.f/sall : 0.f;
  u16* orow = Out + (rowb + q0 + w*32 + qc)*2048 + hh*128;
  #pragma unroll
  for (int d=0; d<4; ++d){
    #pragma unroll
    for (int g2=0; g2<4; ++g2){
      uint2 o;
      o.x = cvtpk(accO[d][g2*4+0] * invv, accO[d][g2*4+1] * invv);
      o.y = cvtpk(accO[d][g2*4+2] * invv, accO[d][g2*4+3] * invv);
      *(uint2*)(orow + d*32 + g2*8 + 4*h) = o;     // d_local = (reg&3)+8*(reg>>2)+4h
    }
  }
}

extern "C" void kernel_launch(void* const* d_in, const int* in_sizes, int n_in,
                              void* d_out, int out_size, void* d_ws, size_t ws_size,
                              hipStream_t stream) {
  (void)in_sizes; (void)n_in; (void)out_size; (void)ws_size;
  const float* x    = (const float*)d_in[0];
  const int*   mask = (const int*)d_in[1];
  const float* Wq   = (const float*)d_in[2];
  const float* bq   = (const float*)d_in[3];
  const float* Wk   = (const float*)d_in[4];
  const float* bk   = (const float*)d_in[5];
  const float* Wv   = (const float*)d_in[6];
  const float* bv   = (const float*)d_in[7];
  const float* Wo   = (const float*)d_in[8];
  const float* bo   = (const float*)d_in[9];

  u16* xbf = (u16*)d_ws;                 // 8388608 elems
  u16* WqT = xbf + 8388608;              // 4194304 each
  u16* WkT = WqT + 4194304;
  u16* WvT = WkT + 4194304;
  u16* WoT = WvT + 4194304;
  u16* Qb  = WoT + 4194304;              // 8388608 each, [B,S,H,D] row-major
  u16* Kb  = Qb + 8388608;
  u16* Vb  = Kb + 8388608;
  u16* Ab  = Vb + 8388608;               // attn out bf16 [B,S,E]
  u16* VTb = Ab + 8388608;               // V transposed [B,H,D,S]

  cast_x_kernel<<<8192, 256, 0, stream>>>(x, xbf);
  cast_transpose_kernel<<<dim3(32,32,4), 256, 0, stream>>>(Wq, Wk, Wv, Wo, WqT, WkT, WvT, WoT);
  gemm_kernel<0><<<dim3(16,32), 256, 0, stream>>>(xbf, WqT, bq, Qb);
  gemm_kernel<0><<<dim3(16,32), 256, 0, stream>>>(xbf, WkT, bk, Kb);
  gemm_kernel<0><<<dim3(16,32), 256, 0, stream>>>(xbf, WvT, bv, Vb);
  rope_kernel<<<dim3(16384,2), 256, 0, stream>>>(Qb, Kb);
  transpose_v_kernel<<<dim3(32,2,32), 256, 0, stream>>>(Vb, VTb);
  attn_kernel<<<dim3(16,16,2), 256, 0, stream>>>(Qb, Kb, VTb, mask, Ab);
  gemm_kernel<1><<<dim3(16,32), 256, 0, stream>>>(Ab, WoT, bo, (float*)d_out);
}

// Round 4
// 411.260 us; speedup vs baseline: 1.0604x; 1.0604x over previous
//
#include <hip/hip_runtime.h>
#include <hip/hip_bf16.h>
#include <cmath>

typedef unsigned short u16;
typedef unsigned int   u32;

using v4f    = __attribute__((ext_vector_type(4)))  float;
using f32x16 = __attribute__((ext_vector_type(16))) float;
using s8v    = __attribute__((ext_vector_type(8)))  short;
using u32x2  = __attribute__((ext_vector_type(2)))  unsigned int;

union Frag { uint4 u; s8v s; };

__device__ __forceinline__ u16 f2bf(float f){
  u32 u = __float_as_uint(f);
  u32 r = u + 0x7fffu + ((u >> 16) & 1u);
  return (u16)(r >> 16);
}
__device__ __forceinline__ float bf2f(u16 h){ return __uint_as_float(((u32)h) << 16); }

// pack two f32 -> one dword of 2 bf16 (RNE), single VALU op (T12 recipe; no builtin on gfx950)
__device__ __forceinline__ u32 cvtpk(float a, float b){
  u32 r;
  asm("v_cvt_pk_bf16_f32 %0, %1, %2" : "=v"(r) : "v"(a), "v"(b));
  return r;
}

// async global->LDS, 16B per lane; LDS dest is wave-uniform base + lane*16
__device__ __forceinline__ void async16(const void* g, void* l){
  __builtin_amdgcn_global_load_lds((__attribute__((address_space(1))) void*)g,
                                   (__attribute__((address_space(3))) void*)l, 16, 0, 0);
}

// ---------------- cast x (fp32 -> bf16) ----------------
__global__ __launch_bounds__(256) void cast_x_kernel(const float* __restrict__ x, u16* __restrict__ xb){
  size_t i = ((size_t)blockIdx.x * 256 + threadIdx.x) * 4;
  float4 v = *(const float4*)(x + i);
  uint2 o;
  o.x = (u32)f2bf(v.x) | ((u32)f2bf(v.y) << 16);
  o.y = (u32)f2bf(v.z) | ((u32)f2bf(v.w) << 16);
  *(uint2*)(xb + i) = o;
}

// ---------------- cast + transpose weights: W[k][n] fp32 -> WT[n][k] bf16 ----------------
__global__ __launch_bounds__(256) void cast_transpose_kernel(
    const float* __restrict__ W0, const float* __restrict__ W1,
    const float* __restrict__ W2, const float* __restrict__ W3,
    u16* __restrict__ T0, u16* __restrict__ T1, u16* __restrict__ T2, u16* __restrict__ T3){
  __shared__ float tile[64][65];
  const float* W = (blockIdx.z==0)?W0:(blockIdx.z==1)?W1:(blockIdx.z==2)?W2:W3;
  u16*         T = (blockIdx.z==0)?T0:(blockIdx.z==1)?T1:(blockIdx.z==2)?T2:T3;
  const int k0 = blockIdx.y*64, n0 = blockIdx.x*64;
  const int t  = threadIdx.x;
  const int rr = t >> 4, c4 = (t & 15) * 4;
  #pragma unroll
  for (int i=0;i<4;i++){
    int k = rr + i*16;
    float4 v = *(const float4*)(W + (size_t)(k0+k)*2048 + n0 + c4);
    tile[k][c4+0]=v.x; tile[k][c4+1]=v.y; tile[k][c4+2]=v.z; tile[k][c4+3]=v.w;
  }
  __syncthreads();
  #pragma unroll
  for (int i=0;i<4;i++){
    int n = rr + i*16;
    uint2 o;
    o.x = (u32)f2bf(tile[c4+0][n]) | ((u32)f2bf(tile[c4+1][n])<<16);
    o.y = (u32)f2bf(tile[c4+2][n]) | ((u32)f2bf(tile[c4+3][n])<<16);
    *(uint2*)(T + (size_t)(n0+n)*2048 + k0 + c4) = o;
  }
}

// ---------------- bf16 MFMA GEMM core (m97-style), shared by fused-QKV and Wo ----------------
// C[128x128 tile] = A[m0..+128][K] * BT[n0..+128][K]^T + bias. LDS tiles 128x64 u16, unpadded,
// 16B-block XOR swizzle: data block b of row r stored at pos b^(r&7).
template<int MODE>   // 0: bf16 out, 1: fp32 out
__device__ __forceinline__ void gemm_tile(const u16* __restrict__ A, const u16* __restrict__ BT,
                                          const float* __restrict__ bias, void* __restrict__ Cout,
                                          int m0, int n0, u16* Asl, u16* Bsl){
  constexpr int K = 2048;
  const int tid  = threadIdx.x;
  const int w    = tid >> 6;
  const int lane = tid & 63;
  const int r    = lane & 15, q = lane >> 4;
  const int wm   = (w >> 1) * 64, wn = (w & 1) * 64;

  v4f acc[4][4];
  #pragma unroll
  for (int i=0;i<4;i++)
    #pragma unroll
    for (int j=0;j<4;j++) acc[i][j] = (v4f)0.f;

  // staging geometry: per instr 8 rows x 8 blocks; wave w covers rows [w*32, w*32+32)
  const int srow = w*32 + (lane>>3);
  const int sblk = (lane&7) ^ ((lane>>3)&7);   // swizzled source block for this lane's LDS slot
  const u16* Ag = A  + (size_t)(m0+srow)*K + sblk*8;
  const u16* Bg = BT + (size_t)(n0+srow)*K + sblk*8;
  u16* Als = Asl + (w*32)*64;
  u16* Bls = Bsl + (w*32)*64;

  for (int kk = 0; kk < K; kk += 64) {
    #pragma unroll
    for (int i=0;i<4;i++){
      async16(Ag + (size_t)i*8*K + kk, Als + i*512);
      async16(Bg + (size_t)i*8*K + kk, Bls + i*512);
    }
    __syncthreads();
    #pragma unroll
    for (int ks=0; ks<2; ++ks) {
      s8v af[4], bfr[4];
      #pragma unroll
      for (int i=0;i<4;i++){
        int rho = wm + i*16 + r;
        int p = (ks*4 + q) ^ (r&7);
        Frag t; t.u = *(const uint4*)(Asl + rho*64 + p*8); af[i] = t.s;
      }
      #pragma unroll
      for (int j=0;j<4;j++){
        int rho = wn + j*16 + r;
        int p = (ks*4 + q) ^ (r&7);
        Frag t; t.u = *(const uint4*)(Bsl + rho*64 + p*8); bfr[j] = t.s;
      }
      #pragma unroll
      for (int i=0;i<4;i++)
        #pragma unroll
        for (int j=0;j<4;j++)
          acc[i][j] = __builtin_amdgcn_mfma_f32_16x16x32_bf16(af[i], bfr[j], acc[i][j], 0, 0, 0);
    }
    __syncthreads();
  }

  float bv[4];
  #pragma unroll
  for (int j=0;j<4;j++) bv[j] = bias[n0 + wn + j*16 + r];

  #pragma unroll
  for (int i=0;i<4;i++){
    #pragma unroll
    for (int j=0;j<4;j++){
      const int gn = n0 + wn + j*16 + r;
      #pragma unroll
      for (int rr2=0; rr2<4; ++rr2){
        const int gm = m0 + wm + i*16 + q*4 + rr2;
        float val = acc[i][j][rr2] + bv[j];
        if (MODE == 0) ((u16*)Cout)[(size_t)gm*2048 + gn] = f2bf(val);
        else           ((float*)Cout)[(size_t)gm*2048 + gn] = val;
      }
    }
  }
}

// fused Q/K/V projection: one grid of 48x32 tiles (~5 blocks/CU resident) -> cross-block
// overlap hides the per-K-step barrier drain that 512-block single-GEMM launches exposed.
__global__ __launch_bounds__(256) void gemm_qkv_kernel(
    const u16* __restrict__ A,
    const u16* __restrict__ WqT, const u16* __restrict__ WkT, const u16* __restrict__ WvT,
    const float* __restrict__ bq, const float* __restrict__ bk, const float* __restrict__ bv,
    u16* __restrict__ Qb, u16* __restrict__ Kb, u16* __restrict__ Vb){
  __shared__ u16 Asl[128*64];
  __shared__ u16 Bsl[128*64];
  const int mat = blockIdx.x >> 4;                 // 0:Q 1:K 2:V
  const u16*   BT   = (mat==0)?WqT:(mat==1)?WkT:WvT;
  const float* bias = (mat==0)?bq :(mat==1)?bk :bv;
  u16*         Cout = (mat==0)?Qb :(mat==1)?Kb :Vb;
  gemm_tile<0>(A, BT, bias, Cout, blockIdx.y*128, (blockIdx.x & 15)*128, Asl, Bsl);
}

// standalone GEMM (used for the Wo projection, fp32 out)
template<int MODE>
__global__ __launch_bounds__(256) void gemm_kernel(const u16* __restrict__ A,
                                                   const u16* __restrict__ BT,
                                                   const float* __restrict__ bias,
                                                   void* __restrict__ Cout){
  __shared__ u16 Asl[128*64];
  __shared__ u16 Bsl[128*64];
  gemm_tile<MODE>(A, BT, bias, Cout, blockIdx.y*128, blockIdx.x*128, Asl, Bsl);
}

// ---------------- RoPE in place on bf16 [B,S,H,D], one wave per (b,s,h) row ----------------
__global__ __launch_bounds__(256) void rope_kernel(u16* __restrict__ Q, u16* __restrict__ Kb){
  const int wrow = blockIdx.x*4 + (threadIdx.x >> 6);  // 0 .. 65535 over (b,s,h)
  const int lane = threadIdx.x & 63;
  u16* P = (blockIdx.y == 0) ? Q : Kb;
  const int s = (wrow >> 4) & 2047;
  const size_t base = (size_t)wrow * 128;
  float invf = exp2f(-(float)lane * 0.20762050593045952f);  // log2(10000)/64
  float angle = (float)s * invf;
  float sn, cs;
  sincosf(angle, &sn, &cs);
  float x_j   = bf2f(P[base + lane]);
  float x_j64 = bf2f(P[base + 64 + lane]);
  float x_2j  = bf2f(P[base + 2*lane]);
  float x_2j1 = bf2f(P[base + 2*lane + 1]);
  float o0 = x_j  * cs - x_2j1 * sn;
  float o1 = x_j64 * cs + x_2j  * sn;
  P[base + lane]      = f2bf(o0);
  P[base + 64 + lane] = f2bf(o1);
}

// ---------------- transpose V: [B,S,H,D] -> VT [B,H,D,S] ----------------
__global__ __launch_bounds__(256) void transpose_v_kernel(const u16* __restrict__ V, u16* __restrict__ VT){
  __shared__ u16 t[64*72];
  const int s0 = blockIdx.x*64;
  const int d0 = blockIdx.y*64;
  const int bh = blockIdx.z;
  const int b = bh >> 4, h = bh & 15;
  const size_t obase = ((size_t)bh*128 + d0)*2048 + s0;
  const int tid = threadIdx.x;
  #pragma unroll
  for (int i=0;i<2;i++){
    int c = tid + i*256;
    int sl = c >> 3, dc = (c & 7) * 8;
    *(uint4*)(t + sl*72 + dc) =
      *(const uint4*)(V + ((size_t)(b*2048 + s0 + sl))*2048 + h*128 + d0 + dc);
  }
  __syncthreads();
  #pragma unroll
  for (int i=0;i<2;i++){
    int c = tid + i*256;
    int dl = c >> 3, sc4 = (c & 7) * 8;
    u16 tmp[8];
    #pragma unroll
    for (int j=0;j<8;j++) tmp[j] = t[(sc4+j)*72 + dl];
    *(uint4*)(VT + obase + (size_t)dl*2048 + sc4) = *(const uint4*)tmp;
  }
}

// ---------------- flash attention v3: double-buffered K/V, in-register softmax ----------------
// 32x32x16 MFMA. Q-tile 128 (4 waves x 32 q-rows), K-tile 64. LDS 64KB: 2 x {K [64][128] + V [128][64]},
// unpadded with 16B-block XOR swizzle (pos = blk ^ (row&7)).
// 2-phase pipeline: stage tile t+1 into buf^1 BEFORE computing tile t; one barrier per iter.
// Swapped QK^T: S^T = mfma(A=K, B=Q); P^T frags via v_cvt_pk_bf16_f32 + permlane32_swap;
// O^T = mfma(A=V^T, B=P^T) -> lane-local 1/l normalization.
__global__ __launch_bounds__(256,2) void attn_kernel(const u16* __restrict__ Q,
                                                     const u16* __restrict__ K,
                                                     const u16* __restrict__ VT,
                                                     const int* __restrict__ mask,
                                                     u16* __restrict__ Out){
  constexpr int S = 2048;
  constexpr float SL2 = 0.08838834764831845f * 1.4426950408889634f;  // 1/sqrt(128) * log2(e)
  __shared__ u16 smem[32768];          // 64 KB: two 32KB buffers

  const int tid = threadIdx.x, w = tid >> 6, lane = tid & 63;
  const int qc = lane & 31;            // owned q-row; also key-row / d-row for A-frag reads
  const int h  = lane >> 5;            // k-slice half (A/B frag: k = 8*h + j)
  const int l7 = lane & 7;
  const int hh = blockIdx.y, b = blockIdx.z;
  const int q0 = blockIdx.x * 128;
  const size_t rowb = (size_t)b * 2048;
  const size_t bhD  = ((size_t)(b*16 + hh)) * 128;

  // Q fragments (B-operand: col = q = qc, k = d = 16t + 8h + j) straight from global (read once)
  s8v qf[8];
  {
    const u16* qp = Q + (rowb + q0 + w*32 + qc)*2048 + hh*128 + h*8;
    #pragma unroll
    for (int t=0;t<8;t++){ Frag f; f.u = *(const uint4*)(qp + t*16); qf[t] = f.s; }
  }

  f32x16 accO[4];                      // O^T: [d-block][16 regs]; row=d local, col=q=qc
  #pragma unroll
  for (int d=0; d<4; d++) accO[d] = (f32x16)0.f;
  float lsum = 0.f;

  const int sr4 = lane >> 4, sp16 = lane & 15;   // K staging: 4 rows x 16 blocks per instr
  const int vr8 = lane >> 3, vp8 = lane & 7;     // V staging: 8 rows x 8 blocks per instr

  // stage K tile [64][128] + V tile [128][64] for key block at key0 into buffer `base`
  auto stage = [&](u16* base, int key0){
    u16* Kd = base;
    u16* Vd = base + 8192;
    #pragma unroll
    for (int i=0;i<4;i++){
      int R = w*16 + i*4;
      int ob = sp16 ^ ((R&7) + sr4);              // (R+sr4)&7: R&7 in {0,4}, sr4<4
      async16(K + (rowb + key0 + R + sr4)*2048 + hh*128 + ob*8, Kd + R*128);
    }
    #pragma unroll
    for (int i=0;i<4;i++){
      int R = w*32 + i*8;
      int ob = vp8 ^ vr8;                         // (R&7)==0
      async16(VT + (bhD + R + vr8)*2048 + key0 + ob*8, Vd + R*64);
    }
  };

  // ---- prologue: stage tile 0, mask row 0 ----
  stage(smem, 0);
  int mv = mask[b*S + lane];
  __syncthreads();                                 // drains vmcnt -> buf0 ready
  unsigned long long bm = __ballot(mv != 0);
  int cur = 0;

  for (int it=0; it<32; ++it){
    // ---- issue next tile's loads before compute (2-phase pipeline) ----
    if (it < 31){
      stage(smem + (cur^1)*16384, (it+1)*64);
      mv = mask[b*S + (it+1)*64 + lane];
    }
    const u16* Ks = smem + cur*16384;              // [64 keys][128 d]
    const u16* Vs = Ks + 8192;                     // [128 d][64 keys]

    #pragma unroll
    for (int nb=0; nb<2; ++nb){
      // ---- S^T[key=nb*32+..][q] = K Q^T ----
      f32x16 sc = (f32x16)0.f;
      __builtin_amdgcn_s_setprio(1);
      #pragma unroll
      for (int t=0;t<8;t++){
        Frag kf; kf.u = *(const uint4*)(Ks + (nb*32 + qc)*128 + (((2*t + h) ^ l7)*8));
        sc = __builtin_amdgcn_mfma_f32_32x32x16_bf16(kf.s, qf[t], sc, 0, 0, 0);
      }
      __builtin_amdgcn_s_setprio(0);
      // ---- P = exp(score/sqrt(d)) (no-max softmax), lane-local row sum ----
      float p[16];
      #pragma unroll
      for (int m=0; m<16; ++m) p[m] = exp2f(sc[m] * SL2);
      if (bm != ~0ull){                            // wave-uniform fast path: mask all valid
        #pragma unroll
        for (int m=0; m<16; ++m){
          int bit = nb*32 + (m&3) + 8*(m>>2) + 4*h;
          if (!((bm >> bit) & 1ull)) p[m] = 0.f;
        }
      }
      #pragma unroll
      for (int m=0; m<16; ++m) lsum += p[m];

      // ---- build P^T B-frags in-register and do PV ----
      #pragma unroll
      for (int g=0; g<2; ++g){                     // 16-key sub-tile -> one frag
        u32 a0 = cvtpk(p[8*g+0], p[8*g+1]);        // keys 4h+{0,1}   (+16g local)
        u32 a1 = cvtpk(p[8*g+2], p[8*g+3]);        // keys 4h+{2,3}
        u32 a2 = cvtpk(p[8*g+4], p[8*g+5]);        // keys 8+4h+{0,1}
        u32 a3 = cvtpk(p[8*g+6], p[8*g+7]);        // keys 8+4h+{2,3}
        u32x2 r0 = __builtin_amdgcn_permlane32_swap(a0, a2, false, false);
        u32x2 r1 = __builtin_amdgcn_permlane32_swap(a1, a3, false, false);
        // frag elems j=0..7 = P[qc][16T + 8h + j]
        Frag pf; pf.u = make_uint4(r0[0], r1[0], r0[1], r1[1]);
        const int T = nb*2 + g;
        __builtin_amdgcn_s_setprio(1);
        #pragma unroll
        for (int d=0; d<4; ++d){
          Frag vf; vf.u = *(const uint4*)(Vs + (d*32 + qc)*64 + (((2*T + h) ^ l7)*8));
          accO[d] = __builtin_amdgcn_mfma_f32_32x32x16_bf16(vf.s, pf.s, accO[d], 0, 0, 0);
        }
        __builtin_amdgcn_s_setprio(0);
      }
    }
    __syncthreads();                               // all waves done with buf[cur]; buf[cur^1] staged
    bm = __ballot(mv != 0);
    cur ^= 1;
  }

  // ---- row sum across the two k-slice halves, normalize, store ----
  float sall = lsum + __shfl_xor(lsum, 32, 64);
  float invv = (sall > 0.f) ? 1.f/sall : 0.f;
  u16* orow = Out + (rowb + q0 + w*32 + qc)*2048 + hh*128;
  #pragma unroll
  for (int d=0; d<4; ++d){
    #pragma unroll
    for (int g2=0; g2<4; ++g2){
      uint2 o;
      o.x = cvtpk(accO[d][g2*4+0] * invv, accO[d][g2*4+1] * invv);
      o.y = cvtpk(accO[d][g2*4+2] * invv, accO[d][g2*4+3] * invv);
      *(uint2*)(orow + d*32 + g2*8 + 4*h) = o;     // d_local = (reg&3)+8*(reg>>2)+4h
    }
  }
}

extern "C" void kernel_launch(void* const* d_in, const int* in_sizes, int n_in,
                              void* d_out, int out_size, void* d_ws, size_t ws_size,
                              hipStream_t stream) {
  (void)in_sizes; (void)n_in; (void)out_size; (void)ws_size;
  const float* x    = (const float*)d_in[0];
  const int*   mask = (const int*)d_in[1];
  const float* Wq   = (const float*)d_in[2];
  const float* bq   = (const float*)d_in[3];
  const float* Wk   = (const float*)d_in[4];
  const float* bk   = (const float*)d_in[5];
  const float* Wv   = (const float*)d_in[6];
  const float* bv   = (const float*)d_in[7];
  const float* Wo   = (const float*)d_in[8];
  const float* bo   = (const float*)d_in[9];

  u16* xbf = (u16*)d_ws;                 // 8388608 elems
  u16* WqT = xbf + 8388608;              // 4194304 each
  u16* WkT = WqT + 4194304;
  u16* WvT = WkT + 4194304;
  u16* WoT = WvT + 4194304;
  u16* Qb  = WoT + 4194304;              // 8388608 each, [B,S,H,D] row-major
  u16* Kb  = Qb + 8388608;
  u16* Vb  = Kb + 8388608;
  u16* Ab  = Vb + 8388608;               // attn out bf16 [B,S,E]
  u16* VTb = Ab + 8388608;               // V transposed [B,H,D,S]

  cast_x_kernel<<<8192, 256, 0, stream>>>(x, xbf);
  cast_transpose_kernel<<<dim3(32,32,4), 256, 0, stream>>>(Wq, Wk, Wv, Wo, WqT, WkT, WvT, WoT);
  gemm_qkv_kernel<<<dim3(48,32), 256, 0, stream>>>(xbf, WqT, WkT, WvT, bq, bk, bv, Qb, Kb, Vb);
  rope_kernel<<<dim3(16384,2), 256, 0, stream>>>(Qb, Kb);
  transpose_v_kernel<<<dim3(32,2,32), 256, 0, stream>>>(Vb, VTb);
  attn_kernel<<<dim3(16,16,2), 256, 0, stream>>>(Qb, Kb, VTb, mask, Ab);
  gemm_kernel<1><<<dim3(16,32), 256, 0, stream>>>(Ab, WoT, bo, (float*)d_out);
}